// Round 4
// baseline (327.090 us; speedup 1.0000x reference)
//
#include <hip/hip_runtime.h>
#include <hip/hip_bf16.h>
#include <math.h>

#define B_CONST 256
#define T_CONST 8192
#define P_CONST 16
#define H_CONST 1024

typedef __bf16 bf16x8 __attribute__((ext_vector_type(8)));
typedef __bf16 bf16x4 __attribute__((ext_vector_type(4)));
typedef float  f32x4  __attribute__((ext_vector_type(4)));

typedef __attribute__((address_space(3))) void       as3_void;
typedef const __attribute__((address_space(1))) void as1_cvoid;

__device__ __forceinline__ void gload_lds16(const void* g, void* l) {
    __builtin_amdgcn_global_load_lds((as1_cvoid*)g, (as3_void*)l, 16, 0, 0);
}

// fast gelu: x * sigmoid(1.5957691 * x * (1 + 0.044715 x^2))
__device__ __forceinline__ float gelu_fast(float x) {
    float z = 1.5957691216057308f * x * __builtin_fmaf(0.044715f, x * x, 1.0f);
    return x * __builtin_amdgcn_rcpf(1.0f + __expf(-z));
}

// ---------------- kernel 1: per-batch valid count (sum of mask) ----------------
__global__ void k_valid(const float* __restrict__ x, int* __restrict__ valid) {
    int b = blockIdx.x;
    const float* row = x + (size_t)b * (T_CONST * 2);
    float s = 0.f;
    for (int t = threadIdx.x; t < T_CONST; t += blockDim.x)
        s += row[2 * t + 1];
    __shared__ float red[256];
    red[threadIdx.x] = s;
    __syncthreads();
    for (int off = 128; off > 0; off >>= 1) {
        if (threadIdx.x < off) red[threadIdx.x] += red[threadIdx.x + off];
        __syncthreads();
    }
    if (threadIdx.x == 0) valid[b] = (int)(red[0] + 0.5f);
}

// ---------------- kernel 2: pc + scan; writes pc (as float) to out tail --------
__global__ void k_scan(const int* __restrict__ valid, int* __restrict__ pc,
                       int* __restrict__ starts, int* __restrict__ cum,
                       float* __restrict__ out_pc) {
    __shared__ int s[B_CONST];
    int t = threadIdx.x;
    int v = valid[t];
    int p = (v + P_CONST - 1) / P_CONST;
    s[t] = p;
    __syncthreads();
    for (int off = 1; off < B_CONST; off <<= 1) {
        int add = (t >= off) ? s[t - off] : 0;
        __syncthreads();
        s[t] += add;
        __syncthreads();
    }
    pc[t] = p;
    cum[t] = s[t];
    starts[t] = s[t] - p;
    out_pc[t] = (float)p;
}

// ---------------- kernel 3: gather patches (total x 32 bf16, K padded) ---------
__global__ void k_gather(const float* __restrict__ x, const int* __restrict__ valid,
                         const int* __restrict__ cum, const int* __restrict__ starts,
                         __bf16* __restrict__ patches, int total) {
    int tid = blockIdx.x * blockDim.x + threadIdx.x;
    if (tid >= total * 32) return;
    int j = tid >> 5, k = tid & 31;
    int lo = 0, hi = B_CONST - 1;
    while (lo < hi) { int mid = (lo + hi) >> 1; if (cum[mid] > j) hi = mid; else lo = mid + 1; }
    int b = lo;
    int p = j - starts[b];
    float v = 0.f;
    if (k < 16) {
        int idx = p * P_CONST + k;
        if (idx < valid[b]) v = x[(size_t)b * (T_CONST * 2) + 2 * idx];
    }
    patches[tid] = (__bf16)v;
}

// ---------------- weight prep: transpose K x N fp32 -> N x K bf16 --------------
__global__ void k_transpose_cvt(const float* __restrict__ W, __bf16* __restrict__ WT,
                                int Kdim, int Ndim) {
    __shared__ float tile[32][33];
    int n0 = blockIdx.x * 32, k0 = blockIdx.y * 32;
    int c = threadIdx.x & 31, r0 = threadIdx.x >> 5;
    for (int r = r0; r < 32; r += 8) tile[r][c] = W[(size_t)(k0 + r) * Ndim + n0 + c];
    __syncthreads();
    for (int r = r0; r < 32; r += 8) WT[(size_t)(n0 + r) * Kdim + k0 + c] = (__bf16)tile[c][r];
}

// w1 is 16 x 1024 -> w1t 1024 x 32 (zero-padded K)
__global__ void k_w1t(const float* __restrict__ w1, __bf16* __restrict__ w1t) {
    int n = blockIdx.x * 256 + threadIdx.x;
    if (n >= H_CONST) return;
    for (int k = 0; k < 32; ++k)
        w1t[n * 32 + k] = (k < 16) ? (__bf16)w1[k * H_CONST + n] : (__bf16)0.f;
}

// ---------------- layer-1 GEMM (K=32): proven R3 128x128 structure -------------
template <bool GELU, typename TOut>
__global__ __launch_bounds__(256) void k_mfma_gemm(
    const __bf16* __restrict__ A, const __bf16* __restrict__ WT,
    const float* __restrict__ bias, TOut* __restrict__ C,
    int M, int N, int K) {
    __shared__ __bf16 As[128][32];
    __shared__ __bf16 Bs[128][32];

    const int lane = threadIdx.x & 63;
    const int wid  = threadIdx.x >> 6;
    const int wr = wid >> 1, wc = wid & 1;

    const int nwg_x = gridDim.x;
    const int orig = blockIdx.y * nwg_x + blockIdx.x;
    const int cpx = (nwg_x * gridDim.y) >> 3;
    const int wgid = (orig & 7) * cpx + (orig >> 3);
    const int brow = (wgid / nwg_x) * 128;
    const int bcol = (wgid % nwg_x) * 128;

    f32x4 acc[4][4];
#pragma unroll
    for (int i = 0; i < 4; ++i)
#pragma unroll
        for (int j = 0; j < 4; ++j)
            acc[i][j] = (f32x4){0.f, 0.f, 0.f, 0.f};

    const int sr = lane >> 2;
    const int sc = (lane & 3) * 8;
    const size_t a_base = (size_t)(brow + wid * 16 + sr) * K + sc;
    const size_t b_base = (size_t)(bcol + wid * 16 + sr) * K + sc;
    const size_t stride64 = (size_t)64 * K;

    const int lr = lane & 15;
    const int lk = (lane >> 4) * 8;

    for (int kt = 0; kt < K; kt += 32) {
        gload_lds16(A  + a_base + kt,            &As[wid * 16][0]);
        gload_lds16(A  + a_base + stride64 + kt, &As[64 + wid * 16][0]);
        gload_lds16(WT + b_base + kt,            &Bs[wid * 16][0]);
        gload_lds16(WT + b_base + stride64 + kt, &Bs[64 + wid * 16][0]);
        __syncthreads();

        bf16x8 af[4], bfr[4];
#pragma unroll
        for (int mf = 0; mf < 4; ++mf)
            af[mf] = *(const bf16x8*)&As[wr * 64 + mf * 16 + lr][lk];
#pragma unroll
        for (int nf = 0; nf < 4; ++nf)
            bfr[nf] = *(const bf16x8*)&Bs[wc * 64 + nf * 16 + lr][lk];
#pragma unroll
        for (int mf = 0; mf < 4; ++mf)
#pragma unroll
            for (int nf = 0; nf < 4; ++nf)
                acc[mf][nf] = __builtin_amdgcn_mfma_f32_16x16x32_bf16(
                    bfr[nf], af[mf], acc[mf][nf], 0, 0, 0);
        __syncthreads();
    }

    const int m_off = lane & 15;
    const int c4 = (lane >> 4) << 2;
#pragma unroll
    for (int nf = 0; nf < 4; ++nf) {
        const int col0 = bcol + wc * 64 + nf * 16 + c4;
        const f32x4 bv = *(const f32x4*)&bias[col0];
#pragma unroll
        for (int mf = 0; mf < 4; ++mf) {
            const int row = brow + wr * 64 + mf * 16 + m_off;
            f32x4 v = acc[mf][nf] + bv;
            if (GELU) {
#pragma unroll
                for (int r = 0; r < 4; ++r) v[r] = gelu_fast(v[r]);
            }
            if constexpr (sizeof(TOut) == 4) {
                *(f32x4*)&C[(size_t)row * N + col0] = v;
            } else {
                bf16x4 o;
#pragma unroll
                for (int r = 0; r < 4; ++r) o[r] = (__bf16)v[r];
                *(bf16x4*)&C[(size_t)row * N + col0] = o;
            }
        }
    }
}

// ---------------- deep-pipelined GEMM (K multiple of 64) -----------------------
// BM=128, BN=256, BK=64, 8 waves (2M x 4N), per-wave 64x64.
// Ring of 3 LDS buffers (144 KiB), staged 2 K-tiles ahead via global_load_lds.
// T2 XOR-swizzle (byte ^= (row&7)<<4) via pre-swizzled GLOBAL source (linear LDS
// dest, rule 21) + swizzled ds_read -> conflict-free b128 reads.
// One vmcnt(12) per K-tile (12 loads stay in flight across barriers, T4).
// Raw s_barrier + compiler memory fences (no __syncthreads vmcnt(0) drain).
#define FENCE() asm volatile("" ::: "memory")

template <bool GELU, typename TOut>
__global__ __launch_bounds__(512, 2) void k_gemm_pipe(
    const __bf16* __restrict__ A, const __bf16* __restrict__ WT,
    const float* __restrict__ bias, TOut* __restrict__ C,
    int M, int N, int K) {
    __shared__ __bf16 As[3][128][64];   // 48 KiB
    __shared__ __bf16 Bs[3][256][64];   // 96 KiB

    const int tid  = threadIdx.x;
    const int lane = tid & 63;
    const int w    = tid >> 6;          // wave 0..7
    const int wr   = w >> 2;            // 0..1  (M dir)
    const int wc   = w & 3;             // 0..3  (N dir)

    // bijective XCD swizzle (nwg = 1028, q=128, r=4)
    const int gx   = gridDim.x;         // N/256 = 4
    const int nwg  = gx * gridDim.y;
    const int orig = blockIdx.y * gx + blockIdx.x;
    const int q = nwg >> 3, r = nwg & 7;
    const int xcd = orig & 7, idx = orig >> 3;
    const int wgid = (xcd < r ? xcd * (q + 1) : r * (q + 1) + (xcd - r) * q) + idx;
    const int brow = (wgid / gx) * 128;
    const int bcol = (wgid % gx) * 256;

    // staging: per wave 2 A-loads + 4 B-loads per K-tile (1 KiB each).
    // LDS linear; global source pre-swizzled so LDS[row][cb] holds
    // global elem (row, cb ^ ((row&7)<<4)).
    const int lr8 = lane >> 3;                       // 0..7
    const int swz = 8 * ((lane & 7) ^ lr8);          // element offset in 64-col row
    const __bf16* Ab = A  + (size_t)(brow + w * 16 + lr8) * K + swz;
    const __bf16* Bb = WT + (size_t)(bcol + w * 32 + lr8) * K + swz;
    const size_t rs8 = (size_t)8 * K;

    char* const As0 = (char*)&As[0][0][0];
    char* const Bs0 = (char*)&Bs[0][0][0];
    const int aw = w * 2048;   // wave's A region within a buffer (2 KiB)
    const int bw = w * 4096;   // wave's B region within a buffer (4 KiB)

#define STAGE(buf, kt)                                                        \
    do {                                                                      \
        char* al = As0 + (buf) * 16384 + aw;                                  \
        char* bl = Bs0 + (buf) * 32768 + bw;                                  \
        gload_lds16(Ab + (kt),            al);                                \
        gload_lds16(Ab + rs8 + (kt),      al + 1024);                         \
        gload_lds16(Bb + (kt),            bl);                                \
        gload_lds16(Bb + rs8 + (kt),      bl + 1024);                         \
        gload_lds16(Bb + 2 * rs8 + (kt),  bl + 2048);                         \
        gload_lds16(Bb + 3 * rs8 + (kt),  bl + 3072);                         \
    } while (0)

    f32x4 acc[4][4];
#pragma unroll
    for (int i = 0; i < 4; ++i)
#pragma unroll
        for (int j = 0; j < 4; ++j)
            acc[i][j] = (f32x4){0.f, 0.f, 0.f, 0.f};

    // fragment-read addressing (swizzled)
    const int lr   = lane & 15;
    const int hi16 = (lane >> 4) * 16;               // byte offset of k-subgroup
    const int rswz = (lane & 7) << 4;                // (row&7)<<4

    const int nt = K >> 6;                           // K-tiles
    STAGE(0, 0);
    { int t1 = (nt > 1) ? 1 : 0; STAGE(1, t1 << 6); }

    for (int t = 0; t < nt; ++t) {
        const int cur = t % 3;
        int tl = t + 2; if (tl > nt - 1) tl = nt - 1;
        STAGE((t + 2) % 3, tl << 6);

        asm volatile("s_waitcnt vmcnt(12)" ::: "memory");  // tile-t loads landed; 12 in flight
        __builtin_amdgcn_s_barrier();
        FENCE();

        const char* ab = As0 + cur * 16384;
        const char* bb = Bs0 + cur * 32768;
#pragma unroll
        for (int kk = 0; kk < 2; ++kk) {
            bf16x8 af[4], bf[4];
            const int cb = (kk * 64 + hi16) ^ rswz;
#pragma unroll
            for (int mf = 0; mf < 4; ++mf)
                af[mf] = *(const bf16x8*)(ab + (wr * 64 + mf * 16 + lr) * 128 + cb);
#pragma unroll
            for (int nf = 0; nf < 4; ++nf)
                bf[nf] = *(const bf16x8*)(bb + (wc * 64 + nf * 16 + lr) * 128 + cb);

            __builtin_amdgcn_s_setprio(1);
#pragma unroll
            for (int mf = 0; mf < 4; ++mf)
#pragma unroll
                for (int nf = 0; nf < 4; ++nf)
                    acc[mf][nf] = __builtin_amdgcn_mfma_f32_16x16x32_bf16(
                        bf[nf], af[mf], acc[mf][nf], 0, 0, 0);
            __builtin_amdgcn_s_setprio(0);
            FENCE();
            __builtin_amdgcn_s_barrier();
            FENCE();
        }
    }
#undef STAGE

    // epilogue: swapped-operand C^T frag -> lane holds 4 consecutive cols of a row
    const int c4 = (lane >> 4) << 2;
#pragma unroll
    for (int nf = 0; nf < 4; ++nf) {
        const int col0 = bcol + wc * 64 + nf * 16 + c4;
        const f32x4 bv = *(const f32x4*)&bias[col0];
#pragma unroll
        for (int mf = 0; mf < 4; ++mf) {
            const int row = brow + wr * 64 + mf * 16 + lr;
            f32x4 v = acc[mf][nf] + bv;
            if (GELU) {
#pragma unroll
                for (int rr = 0; rr < 4; ++rr) v[rr] = gelu_fast(v[rr]);
            }
            if constexpr (sizeof(TOut) == 4) {
                *(f32x4*)&C[(size_t)row * N + col0] = v;
            } else {
                bf16x4 o;
#pragma unroll
                for (int rr = 0; rr < 4; ++rr) o[rr] = (__bf16)v[rr];
                *(bf16x4*)&C[(size_t)row * N + col0] = o;
            }
        }
    }
}

extern "C" void kernel_launch(void* const* d_in, const int* in_sizes, int n_in,
                              void* d_out, int out_size, void* d_ws, size_t ws_size,
                              hipStream_t stream) {
    const float* x  = (const float*)d_in[0];
    const float* w1 = (const float*)d_in[1];
    const float* b1 = (const float*)d_in[2];
    const float* w2 = (const float*)d_in[3];
    const float* b2 = (const float*)d_in[4];
    const float* w3 = (const float*)d_in[5];
    const float* b3 = (const float*)d_in[6];

    const int total = (out_size - B_CONST) / H_CONST;  // 32896
    float* out = (float*)d_out;
    float* out_pc = out + (size_t)total * H_CONST;

    char* ws = (char*)d_ws;
    int* valid  = (int*)ws;
    int* pc     = valid + 256;
    int* starts = pc + 256;
    int* cum    = starts + 256;
    __bf16* w1t = (__bf16*)(ws + 4096);                        // 1024x32
    __bf16* w2t = w1t + (size_t)H_CONST * 32;                  // 1024x1024
    __bf16* w3t = w2t + (size_t)H_CONST * H_CONST;             // 1024x1024
    __bf16* patches = w3t + (size_t)H_CONST * H_CONST;         // total x 32
    __bf16* h1 = patches + (size_t)total * 32;                 // total x 1024
    __bf16* h2 = h1 + (size_t)total * H_CONST;                 // total x 1024

    k_valid<<<B_CONST, 256, 0, stream>>>(x, valid);
    k_scan<<<1, B_CONST, 0, stream>>>(valid, pc, starts, cum, out_pc);
    k_gather<<<(total * 32 + 255) / 256, 256, 0, stream>>>(x, valid, cum, starts, patches, total);
    k_w1t<<<4, 256, 0, stream>>>(w1, w1t);
    dim3 tg(H_CONST / 32, H_CONST / 32);
    k_transpose_cvt<<<tg, 256, 0, stream>>>(w2, w2t, H_CONST, H_CONST);
    k_transpose_cvt<<<tg, 256, 0, stream>>>(w3, w3t, H_CONST, H_CONST);

    // layer 1: K=32 (R3 kernel, 128x128 tiles)
    dim3 g1(H_CONST / 128, total / 128);   // 8 x 257
    k_mfma_gemm<true, __bf16><<<g1, dim3(256), 0, stream>>>(patches, w1t, b1, h1, total, H_CONST, 32);

    // layers 2/3: deep-pipelined kernel, BM=128 x BN=256, 512 threads
    dim3 g2(H_CONST / 256, total / 128);   // 4 x 257 = 1028 blocks
    k_gemm_pipe<true,  __bf16><<<g2, dim3(512), 0, stream>>>(h1, w2t, b2, h2, total, H_CONST, H_CONST);
    k_gemm_pipe<false, float ><<<g2, dim3(512), 0, stream>>>(h2, w3t, b3, out, total, H_CONST, H_CONST);
}

// Round 5
// 269.404 us; speedup vs baseline: 1.2141x; 1.2141x over previous
//
#include <hip/hip_runtime.h>
#include <hip/hip_bf16.h>
#include <math.h>

#define B_CONST 256
#define T_CONST 8192
#define P_CONST 16
#define H_CONST 1024

typedef __bf16 bf16x8 __attribute__((ext_vector_type(8)));
typedef __bf16 bf16x4 __attribute__((ext_vector_type(4)));
typedef float  f32x4  __attribute__((ext_vector_type(4)));

typedef __attribute__((address_space(3))) void       as3_void;
typedef const __attribute__((address_space(1))) void as1_cvoid;

__device__ __forceinline__ void gload_lds16(const void* g, void* l) {
    __builtin_amdgcn_global_load_lds((as1_cvoid*)g, (as3_void*)l, 16, 0, 0);
}

// fast gelu: x * sigmoid(1.5957691 * x * (1 + 0.044715 x^2))
__device__ __forceinline__ float gelu_fast(float x) {
    float z = 1.5957691216057308f * x * __builtin_fmaf(0.044715f, x * x, 1.0f);
    return x * __builtin_amdgcn_rcpf(1.0f + __expf(-z));
}

// ---------------- kernel 1: per-batch valid count (sum of mask) ----------------
__global__ void k_valid(const float* __restrict__ x, int* __restrict__ valid) {
    int b = blockIdx.x;
    const float* row = x + (size_t)b * (T_CONST * 2);
    float s = 0.f;
    for (int t = threadIdx.x; t < T_CONST; t += blockDim.x)
        s += row[2 * t + 1];
    __shared__ float red[256];
    red[threadIdx.x] = s;
    __syncthreads();
    for (int off = 128; off > 0; off >>= 1) {
        if (threadIdx.x < off) red[threadIdx.x] += red[threadIdx.x + off];
        __syncthreads();
    }
    if (threadIdx.x == 0) valid[b] = (int)(red[0] + 0.5f);
}

// ---------------- kernel 2: pc + scan; writes pc (as float) to out tail --------
__global__ void k_scan(const int* __restrict__ valid, int* __restrict__ pc,
                       int* __restrict__ starts, int* __restrict__ cum,
                       float* __restrict__ out_pc) {
    __shared__ int s[B_CONST];
    int t = threadIdx.x;
    int v = valid[t];
    int p = (v + P_CONST - 1) / P_CONST;
    s[t] = p;
    __syncthreads();
    for (int off = 1; off < B_CONST; off <<= 1) {
        int add = (t >= off) ? s[t - off] : 0;
        __syncthreads();
        s[t] += add;
        __syncthreads();
    }
    pc[t] = p;
    cum[t] = s[t];
    starts[t] = s[t] - p;
    out_pc[t] = (float)p;
}

// ---------------- kernel 3: gather patches (total x 32 bf16, K padded) ---------
__global__ void k_gather(const float* __restrict__ x, const int* __restrict__ valid,
                         const int* __restrict__ cum, const int* __restrict__ starts,
                         __bf16* __restrict__ patches, int total) {
    int tid = blockIdx.x * blockDim.x + threadIdx.x;
    if (tid >= total * 32) return;
    int j = tid >> 5, k = tid & 31;
    int lo = 0, hi = B_CONST - 1;
    while (lo < hi) { int mid = (lo + hi) >> 1; if (cum[mid] > j) hi = mid; else lo = mid + 1; }
    int b = lo;
    int p = j - starts[b];
    float v = 0.f;
    if (k < 16) {
        int idx = p * P_CONST + k;
        if (idx < valid[b]) v = x[(size_t)b * (T_CONST * 2) + 2 * idx];
    }
    patches[tid] = (__bf16)v;
}

// ---------------- weight prep: transpose K x N fp32 -> N x K bf16 --------------
__global__ void k_transpose_cvt(const float* __restrict__ W, __bf16* __restrict__ WT,
                                int Kdim, int Ndim) {
    __shared__ float tile[32][33];
    int n0 = blockIdx.x * 32, k0 = blockIdx.y * 32;
    int c = threadIdx.x & 31, r0 = threadIdx.x >> 5;
    for (int r = r0; r < 32; r += 8) tile[r][c] = W[(size_t)(k0 + r) * Ndim + n0 + c];
    __syncthreads();
    for (int r = r0; r < 32; r += 8) WT[(size_t)(n0 + r) * Kdim + k0 + c] = (__bf16)tile[c][r];
}

// w1 is 16 x 1024 -> w1t 1024 x 32 (zero-padded K)
__global__ void k_w1t(const float* __restrict__ w1, __bf16* __restrict__ w1t) {
    int n = blockIdx.x * 256 + threadIdx.x;
    if (n >= H_CONST) return;
    for (int k = 0; k < 32; ++k)
        w1t[n * 32 + k] = (k < 16) ? (__bf16)w1[k * H_CONST + n] : (__bf16)0.f;
}

// ---------------- layer-1 GEMM (K=32): proven R3 128x128 structure -------------
template <bool GELU, typename TOut>
__global__ __launch_bounds__(256) void k_mfma_gemm(
    const __bf16* __restrict__ A, const __bf16* __restrict__ WT,
    const float* __restrict__ bias, TOut* __restrict__ C,
    int M, int N, int K) {
    __shared__ __bf16 As[128][32];
    __shared__ __bf16 Bs[128][32];

    const int lane = threadIdx.x & 63;
    const int wid  = threadIdx.x >> 6;
    const int wr = wid >> 1, wc = wid & 1;

    const int nwg_x = gridDim.x;
    const int orig = blockIdx.y * nwg_x + blockIdx.x;
    const int cpx = (nwg_x * gridDim.y) >> 3;
    const int wgid = (orig & 7) * cpx + (orig >> 3);
    const int brow = (wgid / nwg_x) * 128;
    const int bcol = (wgid % nwg_x) * 128;

    f32x4 acc[4][4];
#pragma unroll
    for (int i = 0; i < 4; ++i)
#pragma unroll
        for (int j = 0; j < 4; ++j)
            acc[i][j] = (f32x4){0.f, 0.f, 0.f, 0.f};

    const int sr = lane >> 2;
    const int sc = (lane & 3) * 8;
    const size_t a_base = (size_t)(brow + wid * 16 + sr) * K + sc;
    const size_t b_base = (size_t)(bcol + wid * 16 + sr) * K + sc;
    const size_t stride64 = (size_t)64 * K;

    const int lr = lane & 15;
    const int lk = (lane >> 4) * 8;

    for (int kt = 0; kt < K; kt += 32) {
        gload_lds16(A  + a_base + kt,            &As[wid * 16][0]);
        gload_lds16(A  + a_base + stride64 + kt, &As[64 + wid * 16][0]);
        gload_lds16(WT + b_base + kt,            &Bs[wid * 16][0]);
        gload_lds16(WT + b_base + stride64 + kt, &Bs[64 + wid * 16][0]);
        __syncthreads();

        bf16x8 af[4], bfr[4];
#pragma unroll
        for (int mf = 0; mf < 4; ++mf)
            af[mf] = *(const bf16x8*)&As[wr * 64 + mf * 16 + lr][lk];
#pragma unroll
        for (int nf = 0; nf < 4; ++nf)
            bfr[nf] = *(const bf16x8*)&Bs[wc * 64 + nf * 16 + lr][lk];
#pragma unroll
        for (int mf = 0; mf < 4; ++mf)
#pragma unroll
            for (int nf = 0; nf < 4; ++nf)
                acc[mf][nf] = __builtin_amdgcn_mfma_f32_16x16x32_bf16(
                    bfr[nf], af[mf], acc[mf][nf], 0, 0, 0);
        __syncthreads();
    }

    const int m_off = lane & 15;
    const int c4 = (lane >> 4) << 2;
#pragma unroll
    for (int nf = 0; nf < 4; ++nf) {
        const int col0 = bcol + wc * 64 + nf * 16 + c4;
        const f32x4 bv = *(const f32x4*)&bias[col0];
#pragma unroll
        for (int mf = 0; mf < 4; ++mf) {
            const int row = brow + wr * 64 + mf * 16 + m_off;
            f32x4 v = acc[mf][nf] + bv;
            if (GELU) {
#pragma unroll
                for (int r = 0; r < 4; ++r) v[r] = gelu_fast(v[r]);
            }
            if constexpr (sizeof(TOut) == 4) {
                *(f32x4*)&C[(size_t)row * N + col0] = v;
            } else {
                bf16x4 o;
#pragma unroll
                for (int r = 0; r < 4; ++r) o[r] = (__bf16)v[r];
                *(bf16x4*)&C[(size_t)row * N + col0] = o;
            }
        }
    }
}

// ---------------- big GEMM: R3 structure + BK=64 + dbuf + T2 swizzle -----------
// 128x128 tile, 4 waves (2x2, 64x64 each), BK=64, 2-phase double buffer:
// STAGE(t+1) issued BEFORE compute(t); one __syncthreads per iter (its vmcnt(0)
// drain waits on loads that have had the whole compute phase to land).
// LDS rows are 128B -> would be 16-way bank conflict; fixed with the R4-proven
// XOR swizzle: linear LDS dest + pre-swizzled global source (rule 21) +
// ^((row&7)<<4) on the ds_read byte offset.
template <bool GELU, typename TOut>
__global__ __launch_bounds__(256) void k_gemm_db(
    const __bf16* __restrict__ A, const __bf16* __restrict__ WT,
    const float* __restrict__ bias, TOut* __restrict__ C,
    int M, int N, int K) {
    __shared__ __bf16 As[2][128][64];   // 32 KiB
    __shared__ __bf16 Bs[2][128][64];   // 32 KiB

    const int lane = threadIdx.x & 63;
    const int wid  = threadIdx.x >> 6;
    const int wr = wid >> 1, wc = wid & 1;

    const int nwg_x = gridDim.x;
    const int orig = blockIdx.y * nwg_x + blockIdx.x;
    const int cpx = (nwg_x * gridDim.y) >> 3;   // nwg % 8 == 0 (2056)
    const int wgid = (orig & 7) * cpx + (orig >> 3);
    const int brow = (wgid / nwg_x) * 128;
    const int bcol = (wgid % nwg_x) * 128;

    f32x4 acc[4][4];
#pragma unroll
    for (int i = 0; i < 4; ++i)
#pragma unroll
        for (int j = 0; j < 4; ++j)
            acc[i][j] = (f32x4){0.f, 0.f, 0.f, 0.f};

    // staging: per wave 32 rows of A + 32 rows of B per K-tile, 8-row chunks.
    // global source pre-swizzled: LDS[row][8j..8j+7] holds global col-group
    // j ^ (row&7)  (row&7 == lr8 since chunk starts are multiples of 8).
    const int lr8 = lane >> 3;                       // 0..7
    const int swz = 8 * ((lane & 7) ^ lr8);
    const __bf16* Ab = A  + (size_t)(brow + wid * 32 + lr8) * K + swz;
    const __bf16* Bb = WT + (size_t)(bcol + wid * 32 + lr8) * K + swz;
    const size_t rs8 = (size_t)8 * K;

#define STG(buf, kt)                                                   \
    do {                                                               \
        gload_lds16(Ab + (kt),           &As[buf][wid * 32][0]);       \
        gload_lds16(Ab + rs8 + (kt),     &As[buf][wid * 32 + 8][0]);   \
        gload_lds16(Ab + 2 * rs8 + (kt), &As[buf][wid * 32 + 16][0]);  \
        gload_lds16(Ab + 3 * rs8 + (kt), &As[buf][wid * 32 + 24][0]);  \
        gload_lds16(Bb + (kt),           &Bs[buf][wid * 32][0]);       \
        gload_lds16(Bb + rs8 + (kt),     &Bs[buf][wid * 32 + 8][0]);   \
        gload_lds16(Bb + 2 * rs8 + (kt), &Bs[buf][wid * 32 + 16][0]);  \
        gload_lds16(Bb + 3 * rs8 + (kt), &Bs[buf][wid * 32 + 24][0]);  \
    } while (0)

    // fragment-read addressing (swizzled)
    const int lr   = lane & 15;
    const int hi16 = (lane >> 4) * 16;   // byte offset of k-subgroup within half
    const int rswz = (lane & 7) << 4;    // (row&7)<<4

    const int nt = K >> 6;
    STG(0, 0);
    __syncthreads();

    for (int t = 0; t < nt; ++t) {
        const int buf = t & 1;
        if (t + 1 < nt) STG(buf ^ 1, (t + 1) << 6);

        const char* ab = (const char*)&As[buf][0][0];
        const char* bb = (const char*)&Bs[buf][0][0];
#pragma unroll
        for (int kk = 0; kk < 2; ++kk) {
            const int cb = (kk * 64 + hi16) ^ rswz;
            bf16x8 af[4], bfr[4];
#pragma unroll
            for (int mf = 0; mf < 4; ++mf)
                af[mf] = *(const bf16x8*)(ab + (wr * 64 + mf * 16 + lr) * 128 + cb);
#pragma unroll
            for (int nf = 0; nf < 4; ++nf)
                bfr[nf] = *(const bf16x8*)(bb + (wc * 64 + nf * 16 + lr) * 128 + cb);
#pragma unroll
            for (int mf = 0; mf < 4; ++mf)
#pragma unroll
                for (int nf = 0; nf < 4; ++nf)
                    acc[mf][nf] = __builtin_amdgcn_mfma_f32_16x16x32_bf16(
                        bfr[nf], af[mf], acc[mf][nf], 0, 0, 0);
        }
        __syncthreads();
    }
#undef STG

    // epilogue: swapped C^T frag -> lane holds 4 consecutive cols of one row
    const int c4 = (lane >> 4) << 2;
#pragma unroll
    for (int nf = 0; nf < 4; ++nf) {
        const int col0 = bcol + wc * 64 + nf * 16 + c4;
        const f32x4 bv = *(const f32x4*)&bias[col0];
#pragma unroll
        for (int mf = 0; mf < 4; ++mf) {
            const int row = brow + wr * 64 + mf * 16 + lr;
            f32x4 v = acc[mf][nf] + bv;
            if (GELU) {
#pragma unroll
                for (int rr = 0; rr < 4; ++rr) v[rr] = gelu_fast(v[rr]);
            }
            if constexpr (sizeof(TOut) == 4) {
                *(f32x4*)&C[(size_t)row * N + col0] = v;
            } else {
                bf16x4 o;
#pragma unroll
                for (int rr = 0; rr < 4; ++rr) o[rr] = (__bf16)v[rr];
                *(bf16x4*)&C[(size_t)row * N + col0] = o;
            }
        }
    }
}

extern "C" void kernel_launch(void* const* d_in, const int* in_sizes, int n_in,
                              void* d_out, int out_size, void* d_ws, size_t ws_size,
                              hipStream_t stream) {
    const float* x  = (const float*)d_in[0];
    const float* w1 = (const float*)d_in[1];
    const float* b1 = (const float*)d_in[2];
    const float* w2 = (const float*)d_in[3];
    const float* b2 = (const float*)d_in[4];
    const float* w3 = (const float*)d_in[5];
    const float* b3 = (const float*)d_in[6];

    const int total = (out_size - B_CONST) / H_CONST;  // 32896
    float* out = (float*)d_out;
    float* out_pc = out + (size_t)total * H_CONST;

    char* ws = (char*)d_ws;
    int* valid  = (int*)ws;
    int* pc     = valid + 256;
    int* starts = pc + 256;
    int* cum    = starts + 256;
    __bf16* w1t = (__bf16*)(ws + 4096);                        // 1024x32
    __bf16* w2t = w1t + (size_t)H_CONST * 32;                  // 1024x1024
    __bf16* w3t = w2t + (size_t)H_CONST * H_CONST;             // 1024x1024
    __bf16* patches = w3t + (size_t)H_CONST * H_CONST;         // total x 32
    __bf16* h1 = patches + (size_t)total * 32;                 // total x 1024
    __bf16* h2 = h1 + (size_t)total * H_CONST;                 // total x 1024

    k_valid<<<B_CONST, 256, 0, stream>>>(x, valid);
    k_scan<<<1, B_CONST, 0, stream>>>(valid, pc, starts, cum, out_pc);
    k_gather<<<(total * 32 + 255) / 256, 256, 0, stream>>>(x, valid, cum, starts, patches, total);
    k_w1t<<<4, 256, 0, stream>>>(w1, w1t);
    dim3 tg(H_CONST / 32, H_CONST / 32);
    k_transpose_cvt<<<tg, 256, 0, stream>>>(w2, w2t, H_CONST, H_CONST);
    k_transpose_cvt<<<tg, 256, 0, stream>>>(w3, w3t, H_CONST, H_CONST);

    // layer 1: K=32 (R3 kernel)
    dim3 g1(H_CONST / 128, total / 128);   // 8 x 257 = 2056, %8 == 0
    k_mfma_gemm<true, __bf16><<<g1, dim3(256), 0, stream>>>(patches, w1t, b1, h1, total, H_CONST, 32);

    // layers 2/3: BK=64 double-buffered kernel, same 128x128 grid
    k_gemm_db<true,  __bf16><<<g1, dim3(256), 0, stream>>>(h1, w2t, b2, h2, total, H_CONST, H_CONST);
    k_gemm_db<false, float ><<<g1, dim3(256), 0, stream>>>(h2, w3t, b3, out, total, H_CONST, H_CONST);
}

// Round 6
// 220.376 us; speedup vs baseline: 1.4842x; 1.2225x over previous
//
#include <hip/hip_runtime.h>
#include <hip/hip_bf16.h>
#include <math.h>

#define B_CONST 256
#define T_CONST 8192
#define P_CONST 16
#define H_CONST 1024

typedef __bf16 bf16x8 __attribute__((ext_vector_type(8)));
typedef __bf16 bf16x4 __attribute__((ext_vector_type(4)));
typedef float  f32x4  __attribute__((ext_vector_type(4)));

typedef __attribute__((address_space(3))) void       as3_void;
typedef const __attribute__((address_space(1))) void as1_cvoid;

__device__ __forceinline__ void gload_lds16(const void* g, void* l) {
    __builtin_amdgcn_global_load_lds((as1_cvoid*)g, (as3_void*)l, 16, 0, 0);
}

// fast gelu: x * sigmoid(1.5957691 * x * (1 + 0.044715 x^2))
__device__ __forceinline__ float gelu_fast(float x) {
    float z = 1.5957691216057308f * x * __builtin_fmaf(0.044715f, x * x, 1.0f);
    return x * __builtin_amdgcn_rcpf(1.0f + __expf(-z));
}

// ---------------- kernel 1: per-batch valid count (sum of mask) ----------------
__global__ void k_valid(const float* __restrict__ x, int* __restrict__ valid) {
    int b = blockIdx.x;
    const float* row = x + (size_t)b * (T_CONST * 2);
    float s = 0.f;
    for (int t = threadIdx.x; t < T_CONST; t += blockDim.x)
        s += row[2 * t + 1];
    __shared__ float red[256];
    red[threadIdx.x] = s;
    __syncthreads();
    for (int off = 128; off > 0; off >>= 1) {
        if (threadIdx.x < off) red[threadIdx.x] += red[threadIdx.x + off];
        __syncthreads();
    }
    if (threadIdx.x == 0) valid[b] = (int)(red[0] + 0.5f);
}

// ---------------- kernel 2: pc + scan; writes pc (as float) to out tail --------
__global__ void k_scan(const int* __restrict__ valid, int* __restrict__ pc,
                       int* __restrict__ starts, int* __restrict__ cum,
                       float* __restrict__ out_pc) {
    __shared__ int s[B_CONST];
    int t = threadIdx.x;
    int v = valid[t];
    int p = (v + P_CONST - 1) / P_CONST;
    s[t] = p;
    __syncthreads();
    for (int off = 1; off < B_CONST; off <<= 1) {
        int add = (t >= off) ? s[t - off] : 0;
        __syncthreads();
        s[t] += add;
        __syncthreads();
    }
    pc[t] = p;
    cum[t] = s[t];
    starts[t] = s[t] - p;
    out_pc[t] = (float)p;
}

// ---------------- kernel 3: gather patches (total x 32 bf16, K padded) ---------
__global__ void k_gather(const float* __restrict__ x, const int* __restrict__ valid,
                         const int* __restrict__ cum, const int* __restrict__ starts,
                         __bf16* __restrict__ patches, int total) {
    int tid = blockIdx.x * blockDim.x + threadIdx.x;
    if (tid >= total * 32) return;
    int j = tid >> 5, k = tid & 31;
    int lo = 0, hi = B_CONST - 1;
    while (lo < hi) { int mid = (lo + hi) >> 1; if (cum[mid] > j) hi = mid; else lo = mid + 1; }
    int b = lo;
    int p = j - starts[b];
    float v = 0.f;
    if (k < 16) {
        int idx = p * P_CONST + k;
        if (idx < valid[b]) v = x[(size_t)b * (T_CONST * 2) + 2 * idx];
    }
    patches[tid] = (__bf16)v;
}

// ---------------- weight prep: transpose K x N fp32 -> N x K bf16 --------------
__global__ void k_transpose_cvt(const float* __restrict__ W, __bf16* __restrict__ WT,
                                int Kdim, int Ndim) {
    __shared__ float tile[32][33];
    int n0 = blockIdx.x * 32, k0 = blockIdx.y * 32;
    int c = threadIdx.x & 31, r0 = threadIdx.x >> 5;
    for (int r = r0; r < 32; r += 8) tile[r][c] = W[(size_t)(k0 + r) * Ndim + n0 + c];
    __syncthreads();
    for (int r = r0; r < 32; r += 8) WT[(size_t)(n0 + r) * Kdim + k0 + c] = (__bf16)tile[c][r];
}

// w1 is 16 x 1024 -> w1t 1024 x 32 (zero-padded K)
__global__ void k_w1t(const float* __restrict__ w1, __bf16* __restrict__ w1t) {
    int n = blockIdx.x * 256 + threadIdx.x;
    if (n >= H_CONST) return;
    for (int k = 0; k < 32; ++k)
        w1t[n * 32 + k] = (k < 16) ? (__bf16)w1[k * H_CONST + n] : (__bf16)0.f;
}

// ---------------- layer-1 GEMM (K=32): proven R3 128x128 structure -------------
template <bool GELU, typename TOut>
__global__ __launch_bounds__(256) void k_mfma_gemm(
    const __bf16* __restrict__ A, const __bf16* __restrict__ WT,
    const float* __restrict__ bias, TOut* __restrict__ C,
    int M, int N, int K) {
    __shared__ __bf16 As[128][32];
    __shared__ __bf16 Bs[128][32];

    const int lane = threadIdx.x & 63;
    const int wid  = threadIdx.x >> 6;
    const int wr = wid >> 1, wc = wid & 1;

    const int nwg_x = gridDim.x;
    const int orig = blockIdx.y * nwg_x + blockIdx.x;
    const int cpx = (nwg_x * gridDim.y) >> 3;
    const int wgid = (orig & 7) * cpx + (orig >> 3);
    const int brow = (wgid / nwg_x) * 128;
    const int bcol = (wgid % nwg_x) * 128;

    f32x4 acc[4][4];
#pragma unroll
    for (int i = 0; i < 4; ++i)
#pragma unroll
        for (int j = 0; j < 4; ++j)
            acc[i][j] = (f32x4){0.f, 0.f, 0.f, 0.f};

    const int sr = lane >> 2;
    const int sc = (lane & 3) * 8;
    const size_t a_base = (size_t)(brow + wid * 16 + sr) * K + sc;
    const size_t b_base = (size_t)(bcol + wid * 16 + sr) * K + sc;
    const size_t stride64 = (size_t)64 * K;

    const int lr = lane & 15;
    const int lk = (lane >> 4) * 8;

    for (int kt = 0; kt < K; kt += 32) {
        gload_lds16(A  + a_base + kt,            &As[wid * 16][0]);
        gload_lds16(A  + a_base + stride64 + kt, &As[64 + wid * 16][0]);
        gload_lds16(WT + b_base + kt,            &Bs[wid * 16][0]);
        gload_lds16(WT + b_base + stride64 + kt, &Bs[64 + wid * 16][0]);
        __syncthreads();

        bf16x8 af[4], bfr[4];
#pragma unroll
        for (int mf = 0; mf < 4; ++mf)
            af[mf] = *(const bf16x8*)&As[wr * 64 + mf * 16 + lr][lk];
#pragma unroll
        for (int nf = 0; nf < 4; ++nf)
            bfr[nf] = *(const bf16x8*)&Bs[wc * 64 + nf * 16 + lr][lk];
#pragma unroll
        for (int mf = 0; mf < 4; ++mf)
#pragma unroll
            for (int nf = 0; nf < 4; ++nf)
                acc[mf][nf] = __builtin_amdgcn_mfma_f32_16x16x32_bf16(
                    bfr[nf], af[mf], acc[mf][nf], 0, 0, 0);
        __syncthreads();
    }

    const int m_off = lane & 15;
    const int c4 = (lane >> 4) << 2;
#pragma unroll
    for (int nf = 0; nf < 4; ++nf) {
        const int col0 = bcol + wc * 64 + nf * 16 + c4;
        const f32x4 bv = *(const f32x4*)&bias[col0];
#pragma unroll
        for (int mf = 0; mf < 4; ++mf) {
            const int row = brow + wr * 64 + mf * 16 + m_off;
            f32x4 v = acc[mf][nf] + bv;
            if (GELU) {
#pragma unroll
                for (int r = 0; r < 4; ++r) v[r] = gelu_fast(v[r]);
            }
            if constexpr (sizeof(TOut) == 4) {
                *(f32x4*)&C[(size_t)row * N + col0] = v;
            } else {
                bf16x4 o;
#pragma unroll
                for (int r = 0; r < 4; ++r) o[r] = (__bf16)v[r];
                *(bf16x4*)&C[(size_t)row * N + col0] = o;
            }
        }
    }
}

// ---------------- big GEMM: single-buffer BK=64, reg-fragment pipelining -------
// 128x128 tile, 4 waves (2x2, 64x64 each), BK=64, LDS 32 KiB single buffer ->
// 3 blocks/CU co-resident (the m97 occupancy that hits 912 TF).
// Per K-tile: sync(stage-t landed) -> read ALL 16 b128 frags to regs (both kk)
// -> sync(block-wide reads done; cheap, no vmem in flight) -> issue STG(t+1)
// into the SAME buffer -> 32 MFMA overlap the 8 staging loads' flight.
// R4/R5-proven XOR swizzle: linear LDS dest + pre-swizzled global source +
// ^((row&7)<<4) on the ds_read byte offset. Measured 0 bank conflicts.
template <bool GELU, typename TOut>
__global__ __launch_bounds__(256, 3) void k_gemm_sb(
    const __bf16* __restrict__ A, const __bf16* __restrict__ WT,
    const float* __restrict__ bias, TOut* __restrict__ C,
    int M, int N, int K) {
    __shared__ __bf16 As[128][64];   // 16 KiB
    __shared__ __bf16 Bs[128][64];   // 16 KiB

    const int lane = threadIdx.x & 63;
    const int wid  = threadIdx.x >> 6;
    const int wr = wid >> 1, wc = wid & 1;

    const int nwg_x = gridDim.x;
    const int orig = blockIdx.y * nwg_x + blockIdx.x;
    const int cpx = (nwg_x * gridDim.y) >> 3;   // nwg % 8 == 0 (2056)
    const int wgid = (orig & 7) * cpx + (orig >> 3);
    const int brow = (wgid / nwg_x) * 128;
    const int bcol = (wgid % nwg_x) * 128;

    f32x4 acc[4][4];
#pragma unroll
    for (int i = 0; i < 4; ++i)
#pragma unroll
        for (int j = 0; j < 4; ++j)
            acc[i][j] = (f32x4){0.f, 0.f, 0.f, 0.f};

    // staging: per wave 32 rows of A + 32 rows of B per K-tile, 8-row chunks.
    // global source pre-swizzled: LDS[row][8j..8j+7] holds global col-group
    // j ^ (row&7).
    const int lr8 = lane >> 3;                       // 0..7
    const int swz = 8 * ((lane & 7) ^ lr8);
    const __bf16* Ab = A  + (size_t)(brow + wid * 32 + lr8) * K + swz;
    const __bf16* Bb = WT + (size_t)(bcol + wid * 32 + lr8) * K + swz;
    const size_t rs8 = (size_t)8 * K;

#define STG(kt)                                                        \
    do {                                                               \
        gload_lds16(Ab + (kt),           &As[wid * 32][0]);            \
        gload_lds16(Ab + rs8 + (kt),     &As[wid * 32 + 8][0]);        \
        gload_lds16(Ab + 2 * rs8 + (kt), &As[wid * 32 + 16][0]);       \
        gload_lds16(Ab + 3 * rs8 + (kt), &As[wid * 32 + 24][0]);       \
        gload_lds16(Bb + (kt),           &Bs[wid * 32][0]);            \
        gload_lds16(Bb + rs8 + (kt),     &Bs[wid * 32 + 8][0]);        \
        gload_lds16(Bb + 2 * rs8 + (kt), &Bs[wid * 32 + 16][0]);       \
        gload_lds16(Bb + 3 * rs8 + (kt), &Bs[wid * 32 + 24][0]);       \
    } while (0)

    // fragment-read addressing (swizzled)
    const int lr   = lane & 15;
    const int hi16 = (lane >> 4) * 16;   // byte offset of k-subgroup within half
    const int rswz = (lane & 7) << 4;    // (row&7)<<4

    const int nt = K >> 6;
    STG(0);

    for (int t = 0; t < nt; ++t) {
        __syncthreads();                 // stage-t loads landed (vmcnt drain)

        const char* ab = (const char*)&As[0][0];
        const char* bb = (const char*)&Bs[0][0];
        bf16x8 af[2][4], bfr[2][4];
#pragma unroll
        for (int kk = 0; kk < 2; ++kk) {
            const int cb = (kk * 64 + hi16) ^ rswz;
#pragma unroll
            for (int mf = 0; mf < 4; ++mf)
                af[kk][mf] = *(const bf16x8*)(ab + (wr * 64 + mf * 16 + lr) * 128 + cb);
#pragma unroll
            for (int nf = 0; nf < 4; ++nf)
                bfr[kk][nf] = *(const bf16x8*)(bb + (wc * 64 + nf * 16 + lr) * 128 + cb);
        }
        __syncthreads();                 // all waves done reading LDS (cheap)

        if (t + 1 < nt) STG((t + 1) << 6);   // next tile flies under the MFMAs

        __builtin_amdgcn_s_setprio(1);
#pragma unroll
        for (int kk = 0; kk < 2; ++kk)
#pragma unroll
            for (int mf = 0; mf < 4; ++mf)
#pragma unroll
                for (int nf = 0; nf < 4; ++nf)
                    acc[mf][nf] = __builtin_amdgcn_mfma_f32_16x16x32_bf16(
                        bfr[kk][nf], af[kk][mf], acc[mf][nf], 0, 0, 0);
        __builtin_amdgcn_s_setprio(0);
    }
#undef STG

    // epilogue: swapped C^T frag -> lane holds 4 consecutive cols of one row
    const int c4 = (lane >> 4) << 2;
#pragma unroll
    for (int nf = 0; nf < 4; ++nf) {
        const int col0 = bcol + wc * 64 + nf * 16 + c4;
        const f32x4 bv = *(const f32x4*)&bias[col0];
#pragma unroll
        for (int mf = 0; mf < 4; ++mf) {
            const int row = brow + wr * 64 + mf * 16 + lr;
            f32x4 v = acc[mf][nf] + bv;
            if (GELU) {
#pragma unroll
                for (int rr = 0; rr < 4; ++rr) v[rr] = gelu_fast(v[rr]);
            }
            if constexpr (sizeof(TOut) == 4) {
                *(f32x4*)&C[(size_t)row * N + col0] = v;
            } else {
                bf16x4 o;
#pragma unroll
                for (int rr = 0; rr < 4; ++rr) o[rr] = (__bf16)v[rr];
                *(bf16x4*)&C[(size_t)row * N + col0] = o;
            }
        }
    }
}

extern "C" void kernel_launch(void* const* d_in, const int* in_sizes, int n_in,
                              void* d_out, int out_size, void* d_ws, size_t ws_size,
                              hipStream_t stream) {
    const float* x  = (const float*)d_in[0];
    const float* w1 = (const float*)d_in[1];
    const float* b1 = (const float*)d_in[2];
    const float* w2 = (const float*)d_in[3];
    const float* b2 = (const float*)d_in[4];
    const float* w3 = (const float*)d_in[5];
    const float* b3 = (const float*)d_in[6];

    const int total = (out_size - B_CONST) / H_CONST;  // 32896
    float* out = (float*)d_out;
    float* out_pc = out + (size_t)total * H_CONST;

    char* ws = (char*)d_ws;
    int* valid  = (int*)ws;
    int* pc     = valid + 256;
    int* starts = pc + 256;
    int* cum    = starts + 256;
    __bf16* w1t = (__bf16*)(ws + 4096);                        // 1024x32
    __bf16* w2t = w1t + (size_t)H_CONST * 32;                  // 1024x1024
    __bf16* w3t = w2t + (size_t)H_CONST * H_CONST;             // 1024x1024
    __bf16* patches = w3t + (size_t)H_CONST * H_CONST;         // total x 32
    __bf16* h1 = patches + (size_t)total * 32;                 // total x 1024
    __bf16* h2 = h1 + (size_t)total * H_CONST;                 // total x 1024

    k_valid<<<B_CONST, 256, 0, stream>>>(x, valid);
    k_scan<<<1, B_CONST, 0, stream>>>(valid, pc, starts, cum, out_pc);
    k_gather<<<(total * 32 + 255) / 256, 256, 0, stream>>>(x, valid, cum, starts, patches, total);
    k_w1t<<<4, 256, 0, stream>>>(w1, w1t);
    dim3 tg(H_CONST / 32, H_CONST / 32);
    k_transpose_cvt<<<tg, 256, 0, stream>>>(w2, w2t, H_CONST, H_CONST);
    k_transpose_cvt<<<tg, 256, 0, stream>>>(w3, w3t, H_CONST, H_CONST);

    // layer 1: K=32 (R3 kernel)
    dim3 g1(H_CONST / 128, total / 128);   // 8 x 257 = 2056, %8 == 0
    k_mfma_gemm<true, __bf16><<<g1, dim3(256), 0, stream>>>(patches, w1t, b1, h1, total, H_CONST, 32);

    // layers 2/3: single-buffer BK=64 pipelined kernel, 3 blocks/CU
    k_gemm_sb<true,  __bf16><<<g1, dim3(256), 0, stream>>>(h1, w2t, b2, h2, total, H_CONST, H_CONST);
    k_gemm_sb<false, float ><<<g1, dim3(256), 0, stream>>>(h2, w3t, b3, out, total, H_CONST, H_CONST);
}